// Round 1
// baseline (896.594 us; speedup 1.0000x reference)
//
#include <hip/hip_runtime.h>

#define N_NODES 100000
#define N_EDGES 1600000
#define IN_DIM 500
#define HID 32
#define N_REL 7
#define OUT_DIM 4
#define N_GRAPHS 16
#define NC 256      // (N_REL + 1) * HID: [root | rel0..rel6]
#define MC 224      // message cols (N_REL * HID)
#define KPAD 512

// dst-bucketing: 64 nodes/bucket, capacity 2048 edges (mean 1024, sigma 32)
#define BK_SHIFT 6
#define BK_NODES 64
#define N_BUCKETS ((N_NODES + BK_NODES - 1) / BK_NODES)   // 1563
#define BK_CAP 2048

typedef __attribute__((ext_vector_type(8))) short bf16x8;
typedef __attribute__((ext_vector_type(4))) float f32x4;

__device__ inline unsigned short f2bf(float f) {
    unsigned u = __float_as_uint(f);
    unsigned r = (u + 0x7FFFu + ((u >> 16) & 1u)) >> 16;
    return (unsigned short)r;
}
__device__ inline float bf2f(unsigned short b) {
    return __uint_as_float((unsigned)b << 16);
}

// ---------------- build Wbf: bf16 B-matrix in MFMA fragment order ----------
__global__ void build_wbf(const float* __restrict__ W_root,
                          const float* __restrict__ W_rel,
                          unsigned short* __restrict__ Wbf) {
    int idx = blockIdx.x * blockDim.x + threadIdx.x;   // 0 .. KPAD*NC-1
    if (idx >= KPAD * NC) return;
    int kk = idx >> 8;
    int n = idx & 255;
    float v = 0.f;
    if (kk < IN_DIM) {
        if (n < HID) v = W_root[kk * HID + n];
        else {
            int r = (n >> 5) - 1;
            v = W_rel[((size_t)r * IN_DIM + kk) * HID + (n & 31)];
        }
    }
    int ks = kk >> 5, q = (kk >> 3) & 3, j = kk & 7;
    Wbf[(size_t)((((ks << 2) + q) << 8) + n) * 8 + j] = f2bf(v);
}

// ---------------- MFMA GEMM: [Hr fp32 | Hm bf16] = bf16(A) @ Wbf ----------
__global__ __launch_bounds__(256, 4) void gemm_mfma(const float* __restrict__ A,
                                                    const uint4* __restrict__ Wbf,
                                                    float* __restrict__ Hr,
                                                    unsigned short* __restrict__ Hm) {
    __shared__ uint4 Alds[32 * 64];   // 32 KB: entry(ksq_local, row^swz)

    const int tid = threadIdx.x;
    const int wave = tid >> 6, lane = tid & 63;
    const int l16 = lane & 15, q = lane >> 4;
    const int row0 = blockIdx.x * 64;
    const int wn = wave * 64;

    int rows_valid = N_NODES - row0; if (rows_valid > 64) rows_valid = 64;
    const float4* Ablk4 = (const float4*)(A + (size_t)row0 * IN_DIM);

    f32x4 acc[4][4];
    #pragma unroll
    for (int mt = 0; mt < 4; mt++)
        #pragma unroll
        for (int nt = 0; nt < 4; nt++)
            #pragma unroll
            for (int r = 0; r < 4; r++) acc[mt][nt][r] = 0.f;

    for (int half = 0; half < 2; half++) {
        if (half) __syncthreads();
        #pragma unroll 4
        for (int it = 0; it < 16; it++) {
            int idx = it * 256 + tid;
            int row = idx >> 6, slot = idx & 63;
            int k = half * 256 + slot * 4;
            float4 v = make_float4(0.f, 0.f, 0.f, 0.f);
            if (row < rows_valid && k < IN_DIM)
                v = Ablk4[row * 125 + (k >> 2)];
            int ksq = slot >> 1;                       // local 0..31
            int e = (ksq << 6) | ((row ^ ksq) & 63);
            ushort4 b;
            b.x = f2bf(v.x); b.y = f2bf(v.y); b.z = f2bf(v.z); b.w = f2bf(v.w);
            *(ushort4*)((unsigned short*)&Alds[e] + (slot & 1) * 4) = b;
        }
        __syncthreads();
        #pragma unroll 2
        for (int ksl = 0; ksl < 8; ksl++) {
            int ksq_l = ksl * 4 + q;
            int ksq_g = half * 32 + ksq_l;
            bf16x8 bfr[4], afr[4];
            #pragma unroll
            for (int nt = 0; nt < 4; nt++) {
                uint4 t = Wbf[(size_t)(ksq_g << 8) + wn + nt * 16 + l16];
                bfr[nt] = *(bf16x8*)&t;
            }
            #pragma unroll
            for (int mt = 0; mt < 4; mt++)
                afr[mt] = *(const bf16x8*)&Alds[(ksq_l << 6) | (((mt * 16 + l16) ^ ksq_l) & 63)];
            #pragma unroll
            for (int mt = 0; mt < 4; mt++)
                #pragma unroll
                for (int nt = 0; nt < 4; nt++)
                    acc[mt][nt] = __builtin_amdgcn_mfma_f32_16x16x32_bf16(
                        afr[mt], bfr[nt], acc[mt][nt], 0, 0, 0);
        }
    }

    #pragma unroll
    for (int mt = 0; mt < 4; mt++) {
        int rbase = row0 + mt * 16 + q * 4;
        #pragma unroll
        for (int r = 0; r < 4; r++) {
            int row = rbase + r;
            if (row < N_NODES) {
                #pragma unroll
                for (int nt = 0; nt < 4; nt++) {
                    int col = wn + nt * 16 + l16;
                    float v = acc[mt][nt][r];
                    if (wave == 0 && nt < 2)            // col < 32: root slice
                        Hr[(size_t)row * HID + col] = v;
                    else
                        Hm[(size_t)row * MC + (col - HID)] = f2bf(v);
                }
            }
        }
    }
}

// ---------------- bucket cursor init ----------------
__global__ void init_bcur(int* __restrict__ bcur) {
    int b = blockIdx.x * blockDim.x + threadIdx.x;
    if (b < N_BUCKETS) bcur[b] = b * BK_CAP;
}

// ---------------- bin edges by dst bucket: (ldst<<20)|(src<<3)|rel ---------
// write window = ~1563 active lines per XCD (L2-resident) -> lines fill with
// many records before eviction, unlike the old per-node cursor scatter.
__global__ __launch_bounds__(256) void bin_edges(const int* __restrict__ src,
                                                 const int* __restrict__ dst,
                                                 const int* __restrict__ attr,
                                                 int* __restrict__ bcur,
                                                 int* __restrict__ rec) {
    int e = blockIdx.x * blockDim.x + threadIdx.x;
    if (e >= N_EDGES) return;
    int d = dst[e];
    int b = d >> BK_SHIFT;
    int p = atomicAdd(&bcur[b], 1);
    rec[p] = ((d & (BK_NODES - 1)) << 20) | (src[e] << 3) | attr[e];
}

// ---------------- bucket aggregation: one block per 64-node bucket ---------
// Phase 1: per-(node,rel) counts in LDS (replaces count_edges + scans).
// Phase 3: gather Hm rows, scale by LDS invcnt, ds_add_f32 into 64x32 tile.
// Phase 4: relu + bias + root, fused graph pooling (replaces pool_kernel).
__global__ __launch_bounds__(256) void bucket_agg(const int* __restrict__ rec,
                                                  const int* __restrict__ bcur,
                                                  const float* __restrict__ bias,
                                                  const unsigned short* __restrict__ Hm,
                                                  const float* __restrict__ Hr,
                                                  const int* __restrict__ batch,
                                                  float* __restrict__ pooled) {
    __shared__ int   s_cnt[BK_NODES * N_REL];     // 1.75 KB
    __shared__ float s_inv[BK_NODES * N_REL];     // 1.75 KB
    __shared__ float s_acc[BK_NODES][HID];        // 8 KB
    __shared__ float s_pool[N_GRAPHS][HID];       // 2 KB

    const int b = blockIdx.x;
    const int t = threadIdx.x;
    const int base = b * BK_CAP;
    const int cnt = bcur[b] - base;
    const int n0 = b << BK_SHIFT;
    const int hw = t >> 5, c = t & 31;

    for (int i = t; i < BK_NODES * N_REL; i += 256) s_cnt[i] = 0;
    for (int i = t; i < BK_NODES * HID; i += 256) ((float*)s_acc)[i] = 0.f;
    for (int i = t; i < N_GRAPHS * HID; i += 256) ((float*)s_pool)[i] = 0.f;
    __syncthreads();

    // phase 1: relation counts per local node
    for (int i = t; i < cnt; i += 256) {
        int q = rec[base + i];
        atomicAdd(&s_cnt[(q >> 20) * N_REL + (q & 7)], 1);
    }
    __syncthreads();
    // phase 2: invert counts
    for (int i = t; i < BK_NODES * N_REL; i += 256) {
        int cc = s_cnt[i];
        s_inv[i] = 1.0f / (float)(cc > 1 ? cc : 1);
    }
    __syncthreads();

    // phase 3: half-wave (32 lanes) per record, 8 records in flight
    int i = hw;
    for (; i + 56 < cnt; i += 64) {
        int q[8];
        float h[8];
        #pragma unroll
        for (int j = 0; j < 8; j++) q[j] = rec[base + i + j * 8];
        #pragma unroll
        for (int j = 0; j < 8; j++)
            h[j] = bf2f(Hm[(size_t)((q[j] >> 3) & 0x1FFFF) * MC + (q[j] & 7) * HID + c]);
        #pragma unroll
        for (int j = 0; j < 8; j++)
            atomicAdd(&s_acc[q[j] >> 20][c],
                      h[j] * s_inv[(q[j] >> 20) * N_REL + (q[j] & 7)]);
    }
    for (; i < cnt; i += 8) {
        int q = rec[base + i];
        float h = bf2f(Hm[(size_t)((q >> 3) & 0x1FFFF) * MC + (q & 7) * HID + c]);
        atomicAdd(&s_acc[q >> 20][c], h * s_inv[(q >> 20) * N_REL + (q & 7)]);
    }
    __syncthreads();

    // phase 4: epilogue + fused pooling
    for (int nl = hw; nl < BK_NODES; nl += 8) {
        int n = n0 + nl;
        if (n < N_NODES) {
            float v = Hr[(size_t)n * HID + c] + bias[c] + s_acc[nl][c];
            v = fmaxf(v, 0.f);
            atomicAdd(&s_pool[batch[n]][c], v);
        }
    }
    __syncthreads();
    for (int i2 = t; i2 < N_GRAPHS * HID; i2 += 256) {
        float v = ((float*)s_pool)[i2];
        if (v != 0.f) atomicAdd(&pooled[i2], v);
    }
}

// ---------------- final FC ----------
__global__ void fc_kernel(const float* __restrict__ pooled, const float* __restrict__ fc_w,
                          const float* __restrict__ fc_b, float* __restrict__ out) {
    int t = threadIdx.x;
    if (t >= N_GRAPHS * OUT_DIM) return;
    int g = t >> 2, o = t & 3;
    float acc = fc_b[o];
    #pragma unroll
    for (int c = 0; c < HID; c++) acc += pooled[g * HID + c] * fc_w[c * OUT_DIM + o];
    out[t] = acc;
}

extern "C" void kernel_launch(void* const* d_in, const int* in_sizes, int n_in,
                              void* d_out, int out_size, void* d_ws, size_t ws_size,
                              hipStream_t stream) {
    const float* node_x  = (const float*)d_in[0];
    const int*   edge_ix = (const int*)d_in[1];
    const int*   e_attr  = (const int*)d_in[2];
    const int*   batch   = (const int*)d_in[3];
    const float* W_rel   = (const float*)d_in[4];
    const float* W_root  = (const float*)d_in[5];
    const float* bias    = (const float*)d_in[6];
    const float* fc_w    = (const float*)d_in[7];
    const float* fc_b    = (const float*)d_in[8];
    float* out = (float*)d_out;

    char* ws = (char*)d_ws;
    size_t off = 0;
    auto alloc = [&](size_t bytes) {
        char* p = ws + off;
        off += (bytes + 255) & ~(size_t)255;
        return p;
    };
    unsigned short* Wbf = (unsigned short*)alloc((size_t)KPAD * NC * 2);   // 256 KB
    float* Hr      = (float*)alloc((size_t)N_NODES * HID * 4);             // 12.8 MB
    unsigned short* Hm = (unsigned short*)alloc((size_t)N_NODES * MC * 2); // 44.8 MB
    int*   rec     = (int*)  alloc((size_t)N_BUCKETS * BK_CAP * 4);        // 12.8 MB
    int*   bcur    = (int*)  alloc((size_t)N_BUCKETS * 4);
    float* pooled  = (float*)alloc((size_t)N_GRAPHS * HID * 4);
    (void)ws_size; (void)in_sizes; (void)n_in; (void)out_size;

    const int* src = edge_ix;
    const int* dst = edge_ix + N_EDGES;

    hipMemsetAsync(pooled, 0, (size_t)N_GRAPHS * HID * 4, stream);

    build_wbf<<<(KPAD * NC + 255) / 256, 256, 0, stream>>>(W_root, W_rel, Wbf);

    init_bcur<<<(N_BUCKETS + 255) / 256, 256, 0, stream>>>(bcur);
    bin_edges<<<(N_EDGES + 255) / 256, 256, 0, stream>>>(src, dst, e_attr, bcur, rec);

    gemm_mfma<<<(N_NODES + 63) / 64, 256, 0, stream>>>(node_x, (const uint4*)Wbf, Hr, Hm);

    bucket_agg<<<N_BUCKETS, 256, 0, stream>>>(rec, bcur, bias, Hm, Hr, batch, pooled);

    fc_kernel<<<1, 64, 0, stream>>>(pooled, fc_w, fc_b, out);
}

// Round 4
// 491.755 us; speedup vs baseline: 1.8233x; 1.8233x over previous
//
#include <hip/hip_runtime.h>

#define N_NODES 100000
#define N_EDGES 1600000
#define IN_DIM 500
#define HID 32
#define N_REL 7
#define OUT_DIM 4
#define N_GRAPHS 16
#define NC 256      // (N_REL + 1) * HID: [root | rel0..rel6]
#define MC 224      // message cols (N_REL * HID)
#define KPAD 512

// dst-bucketing: 64 nodes/bucket; 8 sub-cursors/bucket (indexed blockIdx&7)
// so each sub-region's writes come from one XCD -> full-line fills, no
// cross-XCD partial-dirty write amplification.
#define BK_SHIFT 6
#define BK_NODES 64
#define N_BUCKETS ((N_NODES + BK_NODES - 1) / BK_NODES)   // 1563
#define NSUB 8
#define SUB_CAP 256              // mean 128, sigma ~11 -> no overflow in practice
#define BK_CAP (NSUB * SUB_CAP)  // 2048
#define NPOOL 8                  // pooled partial slices (blockIdx&7)

typedef __attribute__((ext_vector_type(8))) short bf16x8;
typedef __attribute__((ext_vector_type(4))) float f32x4;

__device__ inline unsigned short f2bf(float f) {
    unsigned u = __float_as_uint(f);
    unsigned r = (u + 0x7FFFu + ((u >> 16) & 1u)) >> 16;
    return (unsigned short)r;
}
__device__ inline float bf2f(unsigned short b) {
    return __uint_as_float((unsigned)b << 16);
}

// ---------------- build Wbf: bf16 B-matrix in MFMA fragment order ----------
__global__ void build_wbf(const float* __restrict__ W_root,
                          const float* __restrict__ W_rel,
                          unsigned short* __restrict__ Wbf) {
    int idx = blockIdx.x * blockDim.x + threadIdx.x;   // 0 .. KPAD*NC-1
    if (idx >= KPAD * NC) return;
    int kk = idx >> 8;
    int n = idx & 255;
    float v = 0.f;
    if (kk < IN_DIM) {
        if (n < HID) v = W_root[kk * HID + n];
        else {
            int r = (n >> 5) - 1;
            v = W_rel[((size_t)r * IN_DIM + kk) * HID + (n & 31)];
        }
    }
    int ks = kk >> 5, q = (kk >> 3) & 3, j = kk & 7;
    Wbf[(size_t)((((ks << 2) + q) << 8) + n) * 8 + j] = f2bf(v);
}

// ---------------- MFMA GEMM: [Hr fp32 | Hm bf16] = bf16(A) @ Wbf ----------
__global__ __launch_bounds__(256, 4) void gemm_mfma(const float* __restrict__ A,
                                                    const uint4* __restrict__ Wbf,
                                                    float* __restrict__ Hr,
                                                    unsigned short* __restrict__ Hm) {
    __shared__ uint4 Alds[32 * 64];   // 32 KB: entry(ksq_local, row^swz)

    const int tid = threadIdx.x;
    const int wave = tid >> 6, lane = tid & 63;
    const int l16 = lane & 15, q = lane >> 4;
    const int row0 = blockIdx.x * 64;
    const int wn = wave * 64;

    int rows_valid = N_NODES - row0; if (rows_valid > 64) rows_valid = 64;
    const float4* Ablk4 = (const float4*)(A + (size_t)row0 * IN_DIM);

    f32x4 acc[4][4];
    #pragma unroll
    for (int mt = 0; mt < 4; mt++)
        #pragma unroll
        for (int nt = 0; nt < 4; nt++)
            #pragma unroll
            for (int r = 0; r < 4; r++) acc[mt][nt][r] = 0.f;

    for (int half = 0; half < 2; half++) {
        if (half) __syncthreads();
        #pragma unroll 4
        for (int it = 0; it < 16; it++) {
            int idx = it * 256 + tid;
            int row = idx >> 6, slot = idx & 63;
            int k = half * 256 + slot * 4;
            float4 v = make_float4(0.f, 0.f, 0.f, 0.f);
            if (row < rows_valid && k < IN_DIM)
                v = Ablk4[row * 125 + (k >> 2)];
            int ksq = slot >> 1;                       // local 0..31
            int e = (ksq << 6) | ((row ^ ksq) & 63);
            ushort4 b;
            b.x = f2bf(v.x); b.y = f2bf(v.y); b.z = f2bf(v.z); b.w = f2bf(v.w);
            *(ushort4*)((unsigned short*)&Alds[e] + (slot & 1) * 4) = b;
        }
        __syncthreads();
        #pragma unroll 2
        for (int ksl = 0; ksl < 8; ksl++) {
            int ksq_l = ksl * 4 + q;
            int ksq_g = half * 32 + ksq_l;
            bf16x8 bfr[4], afr[4];
            #pragma unroll
            for (int nt = 0; nt < 4; nt++) {
                uint4 t = Wbf[(size_t)(ksq_g << 8) + wn + nt * 16 + l16];
                bfr[nt] = *(bf16x8*)&t;
            }
            #pragma unroll
            for (int mt = 0; mt < 4; mt++)
                afr[mt] = *(const bf16x8*)&Alds[(ksq_l << 6) | (((mt * 16 + l16) ^ ksq_l) & 63)];
            #pragma unroll
            for (int mt = 0; mt < 4; mt++)
                #pragma unroll
                for (int nt = 0; nt < 4; nt++)
                    acc[mt][nt] = __builtin_amdgcn_mfma_f32_16x16x32_bf16(
                        afr[mt], bfr[nt], acc[mt][nt], 0, 0, 0);
        }
    }

    #pragma unroll
    for (int mt = 0; mt < 4; mt++) {
        int rbase = row0 + mt * 16 + q * 4;
        #pragma unroll
        for (int r = 0; r < 4; r++) {
            int row = rbase + r;
            if (row < N_NODES) {
                #pragma unroll
                for (int nt = 0; nt < 4; nt++) {
                    int col = wn + nt * 16 + l16;
                    float v = acc[mt][nt][r];
                    if (wave == 0 && nt < 2)            // col < 32: root slice
                        Hr[(size_t)row * HID + col] = v;
                    else
                        Hm[(size_t)row * MC + (col - HID)] = f2bf(v);
                }
            }
        }
    }
}

// ---------------- sub-cursor init ----------------
__global__ void init_bcur(int* __restrict__ bcur) {
    int i = blockIdx.x * blockDim.x + threadIdx.x;
    if (i < N_BUCKETS * NSUB) bcur[i] = i * SUB_CAP;
}

// ---------------- bin edges into (bucket, blockIdx&7) sub-regions ----------
// record: (ldst<<20)|(src<<3)|rel. Sub-cursors keep same-address atomic
// chains short (~128) and write regions XCD-exclusive.
__global__ __launch_bounds__(256) void bin_edges(const int* __restrict__ src,
                                                 const int* __restrict__ dst,
                                                 const int* __restrict__ attr,
                                                 int* __restrict__ bcur,
                                                 int* __restrict__ rec) {
    int e = blockIdx.x * blockDim.x + threadIdx.x;
    if (e >= N_EDGES) return;
    int d = dst[e];
    int cur = (d >> BK_SHIFT) * NSUB + (blockIdx.x & (NSUB - 1));
    int p = atomicAdd(&bcur[cur], 1);
    if (p < (cur + 1) * SUB_CAP)   // overflow guard (prob ~ 0)
        rec[p] = ((d & (BK_NODES - 1)) << 20) | (src[e] << 3) | attr[e];
}

// ---------------- per-bucket LDS counting sort + deg/offs/invcnt -----------
// Replaces count_edges + scan1/2/3 + rec_build. Rewrites rec in per-node
// order within the bucket region (gaps between buckets are fine).
__global__ __launch_bounds__(256) void bucket_sort(int* __restrict__ rec,
                                                   const int* __restrict__ bcur,
                                                   int* __restrict__ deg,
                                                   int* __restrict__ offs,
                                                   float* __restrict__ invcnt) {
    __shared__ int h2[BK_NODES * N_REL];   // per-(node,rel) counts
    __shared__ int lcur[BK_NODES];         // scatter cursors
    __shared__ int sorted[BK_CAP];         // 8 KB
    __shared__ int scnt[NSUB];
    __shared__ int s_total;

    const int b = blockIdx.x, t = threadIdx.x;
    const int n0 = b << BK_SHIFT;
    const size_t rbase = (size_t)b * BK_CAP;

    for (int i = t; i < BK_NODES * N_REL; i += 256) h2[i] = 0;
    if (t < NSUB) {
        int c = bcur[b * NSUB + t] - (b * NSUB + t) * SUB_CAP;
        scnt[t] = c < SUB_CAP ? c : SUB_CAP;
    }
    __syncthreads();

    for (int s = 0; s < NSUB; s++) {
        int cs = scnt[s];
        const int* rp = rec + rbase + s * SUB_CAP;
        for (int i = t; i < cs; i += 256) {
            int q = rp[i];
            atomicAdd(&h2[(q >> 20) * N_REL + (q & 7)], 1);
        }
    }
    __syncthreads();

    if (t < BK_NODES) {       // wave 0: per-node totals + exclusive scan
        int tot = 0;
        #pragma unroll
        for (int r = 0; r < N_REL; r++) tot += h2[t * N_REL + r];
        int incl = tot;
        #pragma unroll
        for (int off = 1; off < BK_NODES; off <<= 1) {
            int y = __shfl_up(incl, off, 64);
            if (t >= off) incl += y;
        }
        int excl = incl - tot;
        lcur[t] = excl;
        if (t == BK_NODES - 1) s_total = incl;
        int n = n0 + t;
        if (n < N_NODES) {
            deg[n] = tot;
            offs[n] = (int)rbase + excl;
        }
    }
    int lim = (N_NODES - n0) * N_REL;
    if (lim > BK_NODES * N_REL) lim = BK_NODES * N_REL;
    for (int i = t; i < lim; i += 256) {
        int cc = h2[i];
        invcnt[(size_t)n0 * N_REL + i] = 1.0f / (float)(cc > 1 ? cc : 1);
    }
    __syncthreads();

    for (int s = 0; s < NSUB; s++) {
        int cs = scnt[s];
        const int* rp = rec + rbase + s * SUB_CAP;
        for (int i = t; i < cs; i += 256) {
            int q = rp[i];
            int p = atomicAdd(&lcur[q >> 20], 1);
            if (p < BK_CAP)                       // defensive (cannot trigger)
                sorted[p] = q & 0xFFFFF;          // strip ldst: (src<<3)|rel
        }
    }
    __syncthreads();

    int total = s_total;
    if (total > BK_CAP) total = BK_CAP;           // defensive (cannot trigger)
    for (int i = t; i < total; i += 256) rec[rbase + i] = sorted[i];
}

// ---------------- gather aggregation: one HALF-wave (32 lanes) per node ----
// register accumulation, 8 loads in flight; fused relu+bias+graph pooling.
__global__ __launch_bounds__(256) void gather_agg(const int* __restrict__ rec,
                                                  const int* __restrict__ offs,
                                                  const int* __restrict__ deg,
                                                  const float* __restrict__ invcnt,
                                                  const float* __restrict__ bias,
                                                  const unsigned short* __restrict__ Hm,
                                                  const float* __restrict__ Hr,
                                                  const int* __restrict__ batch,
                                                  float* __restrict__ pooled) {
    __shared__ float lpool[N_GRAPHS][HID];
    const int t = threadIdx.x;
    for (int i = t; i < N_GRAPHS * HID; i += 256) ((float*)lpool)[i] = 0.f;
    __syncthreads();

    const int d = blockIdx.x * 8 + (t >> 5);   // 12500*8 == N_NODES exactly
    const int c = t & 31;

    int dg = deg[d];
    int start = offs[d];
    int end = start + dg;

    float acc = 0.f;
    int i = start;
    for (; i + 7 < end; i += 8) {
        int q0 = rec[i], q1 = rec[i + 1], q2 = rec[i + 2], q3 = rec[i + 3];
        int q4 = rec[i + 4], q5 = rec[i + 5], q6 = rec[i + 6], q7 = rec[i + 7];
        float h0 = bf2f(Hm[(size_t)(q0 >> 3) * MC + (q0 & 7) * HID + c]);
        float h1 = bf2f(Hm[(size_t)(q1 >> 3) * MC + (q1 & 7) * HID + c]);
        float h2 = bf2f(Hm[(size_t)(q2 >> 3) * MC + (q2 & 7) * HID + c]);
        float h3 = bf2f(Hm[(size_t)(q3 >> 3) * MC + (q3 & 7) * HID + c]);
        float h4 = bf2f(Hm[(size_t)(q4 >> 3) * MC + (q4 & 7) * HID + c]);
        float h5 = bf2f(Hm[(size_t)(q5 >> 3) * MC + (q5 & 7) * HID + c]);
        float h6 = bf2f(Hm[(size_t)(q6 >> 3) * MC + (q6 & 7) * HID + c]);
        float h7 = bf2f(Hm[(size_t)(q7 >> 3) * MC + (q7 & 7) * HID + c]);
        acc = fmaf(h0, invcnt[d * N_REL + (q0 & 7)], acc);
        acc = fmaf(h1, invcnt[d * N_REL + (q1 & 7)], acc);
        acc = fmaf(h2, invcnt[d * N_REL + (q2 & 7)], acc);
        acc = fmaf(h3, invcnt[d * N_REL + (q3 & 7)], acc);
        acc = fmaf(h4, invcnt[d * N_REL + (q4 & 7)], acc);
        acc = fmaf(h5, invcnt[d * N_REL + (q5 & 7)], acc);
        acc = fmaf(h6, invcnt[d * N_REL + (q6 & 7)], acc);
        acc = fmaf(h7, invcnt[d * N_REL + (q7 & 7)], acc);
    }
    for (; i < end; i++) {
        int qq = rec[i];
        acc = fmaf(bf2f(Hm[(size_t)(qq >> 3) * MC + (qq & 7) * HID + c]),
                   invcnt[d * N_REL + (qq & 7)], acc);
    }

    float v = Hr[(size_t)d * HID + c] + bias[c] + acc;
    v = fmaxf(v, 0.f);
    atomicAdd(&lpool[batch[d]][c], v);
    __syncthreads();

    // flush to one of NPOOL partial slices (short, ~XCD-local atomic chains)
    float* pp = pooled + (size_t)(blockIdx.x & (NPOOL - 1)) * N_GRAPHS * HID;
    for (int i2 = t; i2 < N_GRAPHS * HID; i2 += 256) {
        float v2 = ((float*)lpool)[i2];
        if (v2 != 0.f) atomicAdd(&pp[i2], v2);
    }
}

// ---------------- final FC (sums the NPOOL partial slices) ----------
__global__ void fc_kernel(const float* __restrict__ pooled, const float* __restrict__ fc_w,
                          const float* __restrict__ fc_b, float* __restrict__ out) {
    int t = threadIdx.x;
    if (t >= N_GRAPHS * OUT_DIM) return;
    int g = t >> 2, o = t & 3;
    float acc = fc_b[o];
    #pragma unroll
    for (int c = 0; c < HID; c++) {
        float p = 0.f;
        #pragma unroll
        for (int k = 0; k < NPOOL; k++)
            p += pooled[(size_t)(k * N_GRAPHS + g) * HID + c];
        acc += p * fc_w[c * OUT_DIM + o];
    }
    out[t] = acc;
}

extern "C" void kernel_launch(void* const* d_in, const int* in_sizes, int n_in,
                              void* d_out, int out_size, void* d_ws, size_t ws_size,
                              hipStream_t stream) {
    const float* node_x  = (const float*)d_in[0];
    const int*   edge_ix = (const int*)d_in[1];
    const int*   e_attr  = (const int*)d_in[2];
    const int*   batch   = (const int*)d_in[3];
    const float* W_rel   = (const float*)d_in[4];
    const float* W_root  = (const float*)d_in[5];
    const float* bias    = (const float*)d_in[6];
    const float* fc_w    = (const float*)d_in[7];
    const float* fc_b    = (const float*)d_in[8];
    float* out = (float*)d_out;

    char* ws = (char*)d_ws;
    size_t off = 0;
    auto alloc = [&](size_t bytes) {
        char* p = ws + off;
        off += (bytes + 255) & ~(size_t)255;
        return p;
    };
    unsigned short* Wbf = (unsigned short*)alloc((size_t)KPAD * NC * 2);   // 256 KB
    float* Hr      = (float*)alloc((size_t)N_NODES * HID * 4);             // 12.8 MB
    unsigned short* Hm = (unsigned short*)alloc((size_t)N_NODES * MC * 2); // 44.8 MB
    int*   rec     = (int*)  alloc((size_t)N_BUCKETS * BK_CAP * 4);        // 12.8 MB
    int*   bcur    = (int*)  alloc((size_t)N_BUCKETS * NSUB * 4);          // 50 KB
    int*   deg     = (int*)  alloc((size_t)N_NODES * 4);
    int*   offsb   = (int*)  alloc((size_t)N_NODES * 4);
    float* invcnt  = (float*)alloc((size_t)N_NODES * N_REL * 4);           // 2.8 MB
    float* pooled  = (float*)alloc((size_t)NPOOL * N_GRAPHS * HID * 4);    // 16 KB
    (void)ws_size; (void)in_sizes; (void)n_in; (void)out_size;

    const int* src = edge_ix;
    const int* dst = edge_ix + N_EDGES;

    hipMemsetAsync(pooled, 0, (size_t)NPOOL * N_GRAPHS * HID * 4, stream);

    build_wbf<<<(KPAD * NC + 255) / 256, 256, 0, stream>>>(W_root, W_rel, Wbf);

    init_bcur<<<(N_BUCKETS * NSUB + 255) / 256, 256, 0, stream>>>(bcur);
    bin_edges<<<(N_EDGES + 255) / 256, 256, 0, stream>>>(src, dst, e_attr, bcur, rec);
    bucket_sort<<<N_BUCKETS, 256, 0, stream>>>(rec, bcur, deg, offsb, invcnt);

    gemm_mfma<<<(N_NODES + 63) / 64, 256, 0, stream>>>(node_x, (const uint4*)Wbf, Hr, Hm);

    gather_agg<<<(N_NODES + 7) / 8, 256, 0, stream>>>(rec, offsb, deg, invcnt,
                                                      bias, Hm, Hr, batch, pooled);

    fc_kernel<<<1, 64, 0, stream>>>(pooled, fc_w, fc_b, out);
}